// Round 1
// baseline (458.581 us; speedup 1.0000x reference)
//
#include <hip/hip_runtime.h>

// Additive (Bahdanau) attention, fused single-pass over encoder_outputs.
// enc: (32, 8192, 256) fp32 is the only big tensor (256 MiB) -> memory-bound,
// roofline ~43us @ 6.3 TB/s. R5 measured 413us total => latency-bound, not BW.
//
// R6 restructure of attn_main (this file):
//  - 1024 blocks x 4 chunks (was 4096 x 1): Breg/qv/vv amortized 4x.
//  - software pipeline: next chunk's enc loads issued into registers BEFORE the
//    MFMA phase; data is consumed (cvt+ds_write) after barrier 1, so the HBM
//    latency hides under MFMA+tanh (~1500 cyc) within-wave.
//  - single 37KB LDS buffer (Af only read in Phase 1, so the staged write of
//    chunk c+1 reuses it after barrier 1). 3 barriers/chunk.
//  - wave0's softmax overlaps the other 7 waves' staging writes.
//  - __launch_bounds__(512,2): empirically (R2) caps at 128 VGPR -> 2 blocks/CU.
//  - attn_finish: 64 blocks (weights split per half), unrolled context loop.
//
// History:
//  R1: launch_bounds(512,4) => 64-VGPR cap => A spilled (WRITE 268MB), 226us
//  R2: (512,2) => 128 VGPR, 32 rows/wave still spills (WRITE 47MB), 209us
//  R3: 16 rows/wave, no spill (VGPR 80) but 224us; occupancy 24% => latency-bound
//  R4: block=256: 191us, occupancy 33%; runtime invariant vs traffic
//  R5: B in regs, A staged once, 4 barriers: 413us on current harness metric
//      (rocprof top-5 shows only 1GiB fillBuffer dispatches ~160us each; all our
//      kernels are individually <159us)

typedef _Float16 f16x8 __attribute__((ext_vector_type(8)));
typedef _Float16 f16x4 __attribute__((ext_vector_type(4)));
typedef float    f32x4 __attribute__((ext_vector_type(4)));

__device__ __forceinline__ float fast_tanh(float x){
  x = fminf(15.f, fmaxf(-15.f, x));
  float e = __expf(2.f * x);
  return (e - 1.f) * __builtin_amdgcn_rcpf(e + 1.f);
}

// ---------------- prep ----------------
__global__ void prep_kernel(const float* __restrict__ hidden, const float* __restrict__ W,
                            const float* __restrict__ bias, _Float16* __restrict__ Bfrag,
                            float* __restrict__ qb)
{
  int blk = blockIdx.x;
  if (blk < 256){
    int tid  = blk * 256 + threadIdx.x;      // 0..65535
    int j    = tid & 7;
    int lane = (tid >> 3) & 63;
    int kc   = (tid >> 9) & 7;
    int nt   = tid >> 12;
    int lc   = lane & 15, q = lane >> 4;
    int row  = nt * 16 + lc;                 // output-k index (B's n)
    int col  = 256 + kc * 32 + q * 8 + j;    // W column (h + 256)
    Bfrag[tid] = (_Float16)W[row * 512 + col];
  } else {
    int b = blk - 256;
    int k = threadIdx.x;
    const float4* hp = (const float4*)(hidden + b * 256);
    const float4* wp = (const float4*)(W + k * 512);
    float s = 0.f;
    for (int i = 0; i < 64; i++){
      float4 h4 = hp[i], w4 = wp[i];
      s += h4.x * w4.x + h4.y * w4.y + h4.z * w4.z + h4.w * w4.w;
    }
    qb[b * 256 + k] = s + bias[k];
  }
}

// ---------------- main ----------------
// grid = 1024 (32 b x 32 groups of 4 chunks), block = 512 (8 waves; 64 rows/chunk;
// wave w owns k-cols [w*32, w*32+32) for ALL 64 rows)
__global__ __launch_bounds__(512, 2) void attn_main(
    const float* __restrict__ enc, const _Float16* __restrict__ Bfrag,
    const float* __restrict__ qb, const float* __restrict__ v,
    float* __restrict__ logits, float* __restrict__ P,
    float* __restrict__ mw, float* __restrict__ lw)
{
  __shared__ _Float16 Af[16384];   // 64 rows x 256 cols, MFMA-A fragment order, 32 KiB
  __shared__ float plg[8][64];     // per-wave partial logits
  __shared__ float sw[64];         // unnormalized softmax weights
  __shared__ float Pl2[2][256];    // context partials (row-halves)

  const int b = blockIdx.x >> 5, grp = blockIdx.x & 31;
  const int tid = threadIdx.x, wv = tid >> 6, lane = tid & 63;
  const int q = lane >> 4, lc = lane & 15;

  // ---- per-wave B fragments (2 n-tiles, 64 VGPRs), loaded ONCE per block ----
  const int nt0 = wv * 2;
  f16x8 Breg[2][8];
  {
    const f16x8* Bsrc = (const f16x8*)Bfrag;
    #pragma unroll
    for (int ntl = 0; ntl < 2; ntl++)
      #pragma unroll
      for (int kc2 = 0; kc2 < 8; kc2++)
        Breg[ntl][kc2] = Bsrc[((nt0 + ntl) * 8 + kc2) * 64 + lane];
  }
  float qv[2], vv[2];
  #pragma unroll
  for (int ntl = 0; ntl < 2; ntl++){
    int col = (nt0 + ntl) * 16 + lc;
    qv[ntl] = qb[b * 256 + col];
    vv[ntl] = v[col];
  }

  // staging geometry: thread t handles row sr = t>>3, k-chunk skc = t&7 (32 cols)
  const int sr = tid >> 3, skc = tid & 7;
  const int smt = sr >> 4, slcr = sr & 15;

  float4 pf[8];

  // ---- initial stage: chunk 0 of this group ----
  {
    const float4* src = (const float4*)(enc + (size_t)(b * 8192 + grp * 256 + sr) * 256 + skc * 32);
    #pragma unroll
    for (int i = 0; i < 8; i++) pf[i] = src[i];
    #pragma unroll
    for (int i = 0; i < 8; i++){
      f16x4 h4;
      h4[0] = (_Float16)pf[i].x; h4[1] = (_Float16)pf[i].y;
      h4[2] = (_Float16)pf[i].z; h4[3] = (_Float16)pf[i].w;
      int idx = (((smt * 8 + skc) * 64 + (i >> 1) * 16 + slcr) * 8 + (i & 1) * 4);
      *(f16x4*)(&Af[idx]) = h4;
    }
  }
  __syncthreads();

  for (int c = 0; c < 4; c++){
    const int chunk = grp * 4 + c;
    const int rowBase = b * 8192 + chunk * 64;

    // ---- issue next chunk's global loads; latency hides under Phase 1 ----
    if (c < 3){
      const float4* src = (const float4*)(enc + (size_t)(rowBase + 64 + sr) * 256 + skc * 32);
      #pragma unroll
      for (int i = 0; i < 8; i++) pf[i] = src[i];
    }

    // ---- Phase 1: GEMM + tanh + partial logits ----
    {
      const f16x8* Afp = (const f16x8*)Af;
      #pragma unroll
      for (int m = 0; m < 4; m++){
        f32x4 acc0 = {0, 0, 0, 0}, acc1 = {0, 0, 0, 0};
        #pragma unroll
        for (int k8 = 0; k8 < 8; k8++){
          f16x8 af = Afp[(m * 8 + k8) * 64 + lane];
          acc0 = __builtin_amdgcn_mfma_f32_16x16x32_f16(af, Breg[0][k8], acc0, 0, 0, 0);
          acc1 = __builtin_amdgcn_mfma_f32_16x16x32_f16(af, Breg[1][k8], acc1, 0, 0, 0);
        }
        // C/D: col = lane&15 (this wave's k-col), row = q*4 + rr (+m*16)
        #pragma unroll
        for (int rr = 0; rr < 4; rr++){
          float s = fast_tanh(acc0[rr] + qv[0]) * vv[0] + fast_tanh(acc1[rr] + qv[1]) * vv[1];
          s += __shfl_xor(s, 1); s += __shfl_xor(s, 2);
          s += __shfl_xor(s, 4); s += __shfl_xor(s, 8);
          if (lc == 0) plg[wv][m * 16 + q * 4 + rr] = s;
        }
      }
    }
    __syncthreads();   // barrier 1: plg ready; all Af reads done

    // ---- Phase 2 (wave 0) overlapped with staging write (all waves) ----
    if (tid < 64){
      float x = 0.f;
      #pragma unroll
      for (int w = 0; w < 8; w++) x += plg[w][tid];
      logits[rowBase + tid] = x;
      float mx = x;
      for (int o = 1; o < 64; o <<= 1) mx = fmaxf(mx, __shfl_xor(mx, o));
      float e = __expf(x - mx);
      sw[tid] = e;
      float s2 = e;
      for (int o = 1; o < 64; o <<= 1) s2 += __shfl_xor(s2, o);
      if (tid == 0){ mw[b * 128 + chunk] = mx; lw[b * 128 + chunk] = s2; }
    }
    // staged write of chunk c+1 into the SAME buffer (all Phase-1 reads are done)
    if (c < 3){
      #pragma unroll
      for (int i = 0; i < 8; i++){
        f16x4 h4;
        h4[0] = (_Float16)pf[i].x; h4[1] = (_Float16)pf[i].y;
        h4[2] = (_Float16)pf[i].z; h4[3] = (_Float16)pf[i].w;
        int idx = (((smt * 8 + skc) * 64 + (i >> 1) * 16 + slcr) * 8 + (i & 1) * 4);
        *(f16x4*)(&Af[idx]) = h4;
      }
    }
    __syncthreads();   // barrier 2: sw ready; Af writes done

    // ---- Phase 3: context partials; coalesced enc re-read (L2-hot) ----
    {
      const int k = tid & 255, h = tid >> 8;        // h = row-half
      const float* ep = enc + (size_t)(rowBase + h * 32) * 256 + k;
      const float* swh = sw + h * 32;
      float s0 = 0.f, s1 = 0.f, s2 = 0.f, s3 = 0.f;
      #pragma unroll
      for (int r4 = 0; r4 < 8; r4++){
        s0 += swh[r4 * 4 + 0] * ep[(size_t)(r4 * 4 + 0) * 256];
        s1 += swh[r4 * 4 + 1] * ep[(size_t)(r4 * 4 + 1) * 256];
        s2 += swh[r4 * 4 + 2] * ep[(size_t)(r4 * 4 + 2) * 256];
        s3 += swh[r4 * 4 + 3] * ep[(size_t)(r4 * 4 + 3) * 256];
      }
      Pl2[h][k] = (s0 + s1) + (s2 + s3);
    }
    __syncthreads();   // barrier 3: Pl2 ready
    if (tid < 256) P[(size_t)(b * 128 + chunk) * 256 + tid] = Pl2[0][tid] + Pl2[1][tid];
  }
}

// ---------------- finish ----------------
// grid = 64 (2 per batch: half 0 also does context; weights split), block = 256
__global__ void attn_finish(const float* __restrict__ logits, const float* __restrict__ P,
                            const float* __restrict__ mw, const float* __restrict__ lw,
                            float* __restrict__ out)
{
  const int b = blockIdx.x >> 1, half = blockIdx.x & 1, t = threadIdx.x;
  __shared__ float sm[128], swl[128], se[128], sML[2];
  if (t < 128){ sm[t] = mw[b * 128 + t]; swl[t] = lw[b * 128 + t]; }
  __syncthreads();
  if (t == 0){
    float M = -1e30f;
    for (int i = 0; i < 128; i++) M = fmaxf(M, sm[i]);
    sML[0] = M;
  }
  __syncthreads();
  const float M = sML[0];
  if (t < 128) se[t] = __expf(sm[t] - M);
  __syncthreads();
  if (t == 0){
    float L = 0.f;
    for (int i = 0; i < 128; i++) L += swl[i] * se[i];
    sML[1] = L;
  }
  __syncthreads();
  const float inv = 1.f / sML[1];
  // context (t = k index) — half 0 only
  if (half == 0){
    float c = 0.f;
    #pragma unroll 8
    for (int ch = 0; ch < 128; ch++) c += se[ch] * P[(size_t)(b * 128 + ch) * 256 + t];
    out[b * 256 + t] = c * inv;
  }
  // attention weights — each half writes 4096
  const float* lg = logits + (size_t)b * 8192 + half * 4096;
  float* ao = out + 8192 + (size_t)b * 8192 + half * 4096;
  #pragma unroll
  for (int s2 = 0; s2 < 16; s2++) ao[s2 * 256 + t] = __expf(lg[s2 * 256 + t] - M) * inv;
}

extern "C" void kernel_launch(void* const* d_in, const int* in_sizes, int n_in,
                              void* d_out, int out_size, void* d_ws, size_t ws_size,
                              hipStream_t stream)
{
  const float* hidden = (const float*)d_in[0];   // (1,32,256)
  const float* enc    = (const float*)d_in[1];   // (32,8192,256)
  const float* W      = (const float*)d_in[2];   // (256,512)
  const float* bias   = (const float*)d_in[3];   // (256,)
  const float* v      = (const float*)d_in[4];   // (256,)
  float* out = (float*)d_out;

  char* ws = (char*)d_ws;
  _Float16* Bfrag = (_Float16*)ws;                                      // 128 KiB
  float* qb     = (float*)(ws + (128 << 10));                           // 32 KiB
  float* logits = (float*)(ws + (160 << 10));                           // 1 MiB
  float* P      = (float*)(ws + (160 << 10) + (1 << 20));               // 4 MiB (4096*256*4)
  float* mw     = (float*)(ws + (160 << 10) + (5 << 20));               // 16 KiB
  float* lw     = (float*)(ws + (160 << 10) + (5 << 20) + (16 << 10));  // 16 KiB

  prep_kernel<<<288, 256, 0, stream>>>(hidden, W, bias, Bfrag, qb);
  attn_main<<<1024, 512, 0, stream>>>(enc, Bfrag, qb, v, logits, P, mw, lw);
  attn_finish<<<64, 256, 0, stream>>>(logits, P, mw, lw, out);
}

// Round 2
// 419.067 us; speedup vs baseline: 1.0943x; 1.0943x over previous
//
#include <hip/hip_runtime.h>

// Additive (Bahdanau) attention, fused single-pass over encoder_outputs.
// enc: (32, 8192, 256) fp32 is the only big tensor (256 MiB) -> HBM floor ~41us.
//
// R7: wave-autonomous restructure. R6 counters (attn_main 178us, MfmaUtil 7.6%,
// VALUBusy 18%, occ 22%, 7.3M LDS bank conflicts) showed a barrier-lockstep
// latency-bound kernel. R7 removes ALL main-loop barriers:
//  - scores^T: A-operand = We-frags (prep's Bfrag, unchanged — A/B fragment lane
//    maps are identical for 16x16x32_f16), B-operand = enc rows loaded DIRECTLY
//    global->regs in fragment order (kills the bank-conflicted ds_write staging).
//  - output D[kout][row]: v-dot accumulates IN-LANE over (rr,nt); only 2 shfls
//    to finish logits; each wave owns 32 rows end-to-end (GEMM+softmax+context).
//  - We (128KB f16) staged ONCE per block in LDS, read-only by all 16 waves.
//  - context: f32 enc re-read, 1 coalesced row per wave-load, weights via
//    readlane broadcast; numerics identical to R6's passing context path.
//  - next chunk's enc frags loaded before context phase (regs free post-MFMA).
// grid 256 x 1024 thr (16 waves, 1 block/CU, 130KB LDS); 2 chunks of 32 rows/wave.
//
// History:
//  R2: (512,2) 128 VGPR: 209us   R4: block=256: 191us
//  R5: B in regs, A staged, 4 barriers: ~150-160us (not in top5)
//  R6: 4-chunk pipeline: 178us, occ 22%, MfmaUtil 7.6% -> latency-bound, barriers

typedef _Float16 f16x8 __attribute__((ext_vector_type(8)));
typedef float    f32x4 __attribute__((ext_vector_type(4)));

__device__ __forceinline__ float fast_tanh(float x){
  x = fminf(15.f, fmaxf(-15.f, x));
  float e = __expf(2.f * x);
  return (e - 1.f) * __builtin_amdgcn_rcpf(e + 1.f);
}

__device__ __forceinline__ float lane_bcast(float x, int l){
  return __uint_as_float(__builtin_amdgcn_readlane(__float_as_uint(x), l));
}

// ---------------- prep (unchanged) ----------------
__global__ void prep_kernel(const float* __restrict__ hidden, const float* __restrict__ W,
                            const float* __restrict__ bias, _Float16* __restrict__ Bfrag,
                            float* __restrict__ qb)
{
  int blk = blockIdx.x;
  if (blk < 256){
    int tid  = blk * 256 + threadIdx.x;      // 0..65535
    int j    = tid & 7;
    int lane = (tid >> 3) & 63;
    int kc   = (tid >> 9) & 7;
    int nt   = tid >> 12;
    int lc   = lane & 15, q = lane >> 4;
    int row  = nt * 16 + lc;                 // output-k index
    int col  = 256 + kc * 32 + q * 8 + j;    // W column (h + 256)
    Bfrag[tid] = (_Float16)W[row * 512 + col];
  } else {
    int b = blk - 256;
    int k = threadIdx.x;
    const float4* hp = (const float4*)(hidden + b * 256);
    const float4* wp = (const float4*)(W + k * 512);
    float s = 0.f;
    for (int i = 0; i < 64; i++){
      float4 h4 = hp[i], w4 = wp[i];
      s += h4.x * w4.x + h4.y * w4.y + h4.z * w4.z + h4.w * w4.w;
    }
    qb[b * 256 + k] = s + bias[k];
  }
}

// ---------------- main ----------------
// grid = 256 (32 b x 8 slabs of 1024 rows), block = 1024 (16 waves).
// wave w owns rows [w*64, w*64+64) of its slab = 2 chunks of 32 rows, fully
// independent after the one staging barrier.
__global__ __launch_bounds__(1024) void attn_main(
    const float* __restrict__ enc, const _Float16* __restrict__ Bfrag,
    const float* __restrict__ qb, const float* __restrict__ v,
    float* __restrict__ logits, float* __restrict__ P,
    float* __restrict__ mw, float* __restrict__ lw)
{
  __shared__ _Float16 Wf[65536];   // 128 KiB: We fragments (A-operand), frag order
  __shared__ float2 qv2[256];      // {qb[b][k], v[k]}

  const int tid = threadIdx.x, wv = tid >> 6, lane = tid & 63;
  const int q = lane >> 4, lc = lane & 15;
  const int b = blockIdx.x >> 3, slab = blockIdx.x & 7;

  // ---- stage We-frags (128 KiB) + qv2, ONCE per block ----
  {
    const float4* src = (const float4*)Bfrag;
    float4* dst = (float4*)Wf;
    #pragma unroll
    for (int i = 0; i < 8; i++) dst[tid + i * 1024] = src[tid + i * 1024];
    if (tid < 256) qv2[tid] = make_float2(qb[b * 256 + tid], v[tid]);
  }
  __syncthreads();           // the ONLY barrier

  const f16x8* Wl = (const f16x8*)Wf;
  const int rowBase0 = b * 8192 + (slab * 32 + wv * 2) * 32;

  // enc B-fragment loader: lane holds row (base+lc [+16 for tile 1]),
  // cols q*8..q*8+7 (+kc*32). Lines shared by lane pairs (l, l+16) -> coalesced.
  f16x8 bf[2][8];
  #define LOAD_BF(base)                                                     \
  {                                                                         \
    const float* er0 = enc + (size_t)((base) + lc) * 256 + q * 8;           \
    _Pragma("unroll")                                                       \
    for (int t = 0; t < 2; t++){                                            \
      const float* er = er0 + t * 16 * 256;                                 \
      _Pragma("unroll")                                                     \
      for (int kc = 0; kc < 8; kc++){                                       \
        float4 x0 = *(const float4*)(er + kc * 32);                         \
        float4 x1 = *(const float4*)(er + kc * 32 + 4);                     \
        f16x8 h;                                                            \
        h[0]=(_Float16)x0.x; h[1]=(_Float16)x0.y;                           \
        h[2]=(_Float16)x0.z; h[3]=(_Float16)x0.w;                           \
        h[4]=(_Float16)x1.x; h[5]=(_Float16)x1.y;                           \
        h[6]=(_Float16)x1.z; h[7]=(_Float16)x1.w;                           \
        bf[t][kc] = h;                                                      \
      }                                                                     \
    }                                                                       \
  }

  LOAD_BF(rowBase0)

  for (int ci = 0; ci < 2; ci++){
    const int rowBase = rowBase0 + ci * 32;
    const int cid = b * 256 + slab * 32 + wv * 2 + ci;

    // ---- scores^T GEMM: D[kout = q*4+rr (+16nt)][row = lc (+16t)] ----
    float lg0 = 0.f, lg1 = 0.f;
    #pragma unroll 2
    for (int nt = 0; nt < 16; nt++){
      f32x4 acc0 = {0, 0, 0, 0}, acc1 = {0, 0, 0, 0};
      #pragma unroll
      for (int kc = 0; kc < 8; kc++){
        f16x8 a = Wl[(nt * 8 + kc) * 64 + lane];
        acc0 = __builtin_amdgcn_mfma_f32_16x16x32_f16(a, bf[0][kc], acc0, 0, 0, 0);
        acc1 = __builtin_amdgcn_mfma_f32_16x16x32_f16(a, bf[1][kc], acc1, 0, 0, 0);
      }
      #pragma unroll
      for (int rr = 0; rr < 4; rr++){
        float2 c = qv2[nt * 16 + q * 4 + rr];
        lg0 += fast_tanh(acc0[rr] + c.x) * c.y;
        lg1 += fast_tanh(acc1[rr] + c.x) * c.y;
      }
    }
    // finish logits: sum the 4 kout-groups (q); result replicated over q
    lg0 += __shfl_xor(lg0, 16); lg0 += __shfl_xor(lg0, 32);
    lg1 += __shfl_xor(lg1, 16); lg1 += __shfl_xor(lg1, 32);
    if (q == 0){
      logits[rowBase + lc]      = lg0;
      logits[rowBase + 16 + lc] = lg1;
    }
    // ---- wave-local softmax over 32 rows ----
    float m = fmaxf(lg0, lg1);
    m = fmaxf(m, __shfl_xor(m, 1)); m = fmaxf(m, __shfl_xor(m, 2));
    m = fmaxf(m, __shfl_xor(m, 4)); m = fmaxf(m, __shfl_xor(m, 8));
    float e0 = __expf(lg0 - m), e1 = __expf(lg1 - m);
    float ls = e0 + e1;
    ls += __shfl_xor(ls, 1); ls += __shfl_xor(ls, 2);
    ls += __shfl_xor(ls, 4); ls += __shfl_xor(ls, 8);
    if (lane == 0){ mw[cid] = m; lw[cid] = ls; }

    // ---- prefetch next chunk's fragments (bf regs are free now) ----
    if (ci == 0) LOAD_BF(rowBase0 + 32)

    // ---- context: f32 enc re-read (L2-hot), lane owns cols [lane*4, lane*4+4) ----
    float4 ctx = make_float4(0.f, 0.f, 0.f, 0.f);
    const float* ep = enc + (size_t)rowBase * 256 + lane * 4;
    #pragma unroll
    for (int r = 0; r < 16; r++){
      float w0 = lane_bcast(e0, r);          // weight of row r
      float w1 = lane_bcast(e1, r);          // weight of row 16+r
      float4 a  = *(const float4*)(ep + (size_t)r * 256);
      float4 b4 = *(const float4*)(ep + (size_t)(r + 16) * 256);
      ctx.x += w0 * a.x + w1 * b4.x;
      ctx.y += w0 * a.y + w1 * b4.y;
      ctx.z += w0 * a.z + w1 * b4.z;
      ctx.w += w0 * a.w + w1 * b4.w;
    }
    *(float4*)(P + (size_t)cid * 256 + lane * 4) = ctx;
  }
  #undef LOAD_BF
}

// ---------------- finish ----------------
// grid = 64 (2 per batch: half 0 also does context; weights split), block = 256
__global__ void attn_finish(const float* __restrict__ logits, const float* __restrict__ P,
                            const float* __restrict__ mw, const float* __restrict__ lw,
                            float* __restrict__ out)
{
  const int b = blockIdx.x >> 1, half = blockIdx.x & 1, t = threadIdx.x;
  __shared__ float se[256], red[8];
  float mv = mw[b * 256 + t], lv = lw[b * 256 + t];
  float m = mv;
  #pragma unroll
  for (int o = 1; o < 64; o <<= 1) m = fmaxf(m, __shfl_xor(m, o));
  if ((t & 63) == 0) red[t >> 6] = m;
  __syncthreads();
  const float M = fmaxf(fmaxf(red[0], red[1]), fmaxf(red[2], red[3]));
  float e = __expf(mv - M);
  se[t] = e;
  float l = e * lv;
  #pragma unroll
  for (int o = 1; o < 64; o <<= 1) l += __shfl_xor(l, o);
  if ((t & 63) == 0) red[4 + (t >> 6)] = l;
  __syncthreads();
  const float L = red[4] + red[5] + red[6] + red[7];
  const float inv = 1.f / L;
  if (half == 0){
    float c0 = 0.f, c1 = 0.f;
    #pragma unroll 8
    for (int ch = 0; ch < 128; ch++){
      c0 += se[ch]       * P[(size_t)(b * 256 + ch) * 256 + t];
      c1 += se[ch + 128] * P[(size_t)(b * 256 + 128 + ch) * 256 + t];
    }
    out[b * 256 + t] = (c0 + c1) * inv;
  }
  const float* lg = logits + (size_t)b * 8192 + half * 4096;
  float* ao = out + 8192 + (size_t)b * 8192 + half * 4096;
  #pragma unroll
  for (int s2 = 0; s2 < 16; s2++) ao[s2 * 256 + t] = __expf(lg[s2 * 256 + t] - M) * inv;
}

extern "C" void kernel_launch(void* const* d_in, const int* in_sizes, int n_in,
                              void* d_out, int out_size, void* d_ws, size_t ws_size,
                              hipStream_t stream)
{
  const float* hidden = (const float*)d_in[0];   // (1,32,256)
  const float* enc    = (const float*)d_in[1];   // (32,8192,256)
  const float* W      = (const float*)d_in[2];   // (256,512)
  const float* bias   = (const float*)d_in[3];   // (256,)
  const float* v      = (const float*)d_in[4];   // (256,)
  float* out = (float*)d_out;

  char* ws = (char*)d_ws;
  _Float16* Bfrag = (_Float16*)ws;                                       // 128 KiB
  float* qb     = (float*)(ws + (128 << 10));                            // 32 KiB
  float* logits = (float*)(ws + (160 << 10));                            // 1 MiB
  float* P      = (float*)(ws + (160 << 10) + (1 << 20));                // 8 MiB (8192*256*4)
  float* mw     = (float*)(ws + (160 << 10) + (9 << 20));                // 32 KiB
  float* lw     = (float*)(ws + (160 << 10) + (9 << 20) + (32 << 10));   // 32 KiB

  prep_kernel<<<288, 256, 0, stream>>>(hidden, W, bias, Bfrag, qb);
  attn_main<<<256, 1024, 0, stream>>>(enc, Bfrag, qb, v, logits, P, mw, lw);
  attn_finish<<<64, 256, 0, stream>>>(logits, P, mw, lw, out);
}